// Round 5
// baseline (1674.876 us; speedup 1.0000x reference)
//
#include <hip/hip_runtime.h>

// Problem dims (fixed by reference)
#define NROWS  8192
#define INDIM  2048
#define LATDIM 16384
#define HIDDIM 2048
#define TOPK   32

// DELTA = 2 * max bf16-GEMM latent error (err_max ~ 6e-3 at 8 sigma).
// certain: approx > hi + 2*err  => provably in top-32 (beaters <= 31)
// candidate floor: member => approx > lo - 2*err
#define DELTA    0.012f
#define CAND_MAX 128

typedef __attribute__((ext_vector_type(8))) short bf16x8;
typedef __attribute__((ext_vector_type(4))) float f32x4;

// f32 -> bf16 round-to-nearest-even (bits)
__device__ __forceinline__ unsigned short f2bf(float f) {
  unsigned u = __float_as_uint(f);
  unsigned r = 0x7FFFu + ((u >> 16) & 1u);
  return (unsigned short)((u + r) >> 16);
}
// async global->LDS, 16B per lane; lds dest must be wave-uniform base (+lane*16)
__device__ __forceinline__ void gload16(const void* g, void* l) {
  __builtin_amdgcn_global_load_lds(
      (const __attribute__((address_space(1))) void*)g,
      (__attribute__((address_space(3))) void*)l, 16, 0, 0);
}

// ---------------- K1: x fp32 -> bf16 ----------------
__global__ __launch_bounds__(256)
void k_cvt_x(const float4* __restrict__ in, ushort4* __restrict__ out, int n4) {
  int i = blockIdx.x * 256 + threadIdx.x;
  if (i >= n4) return;
  float4 v = in[i];
  ushort4 o;
  o.x = f2bf(v.x); o.y = f2bf(v.y); o.z = f2bf(v.z); o.w = f2bf(v.w);
  out[i] = o;
}

// ---------------- K2: encoder [2048][16384] -> encT f32 [16384][2048] + encTb bf16 ----------------
__global__ __launch_bounds__(256)
void k_trans_enc(const float* __restrict__ enc,
                 float* __restrict__ encT,
                 unsigned short* __restrict__ encTb) {
  __shared__ float tile[32][33];
  const int c0 = blockIdx.x * 32;  // latent col base
  const int r0 = blockIdx.y * 32;  // input-dim row base
  const int tx = threadIdx.x, ty = threadIdx.y;
  #pragma unroll
  for (int i = ty; i < 32; i += 8)
    tile[i][tx] = enc[(size_t)(r0 + i) * LATDIM + c0 + tx];
  __syncthreads();
  #pragma unroll
  for (int i = ty; i < 32; i += 8) {
    float v = tile[tx][i];
    size_t o = (size_t)(c0 + i) * INDIM + r0 + tx;
    encT[o]  = v;
    encTb[o] = f2bf(v);
  }
}

// ---------------- K3: bf16 MFMA GEMM, 256x256 tile, 4-phase counted-vmcnt schedule ----------------
#define KTILES 32

#define AREG(p, kh) (((p) * 2 + (kh)) * 16384)
#define BREG(p, kh) (65536 + ((p) * 2 + (kh)) * 16384)

#define MFMAQ(MQ)                                                             \
  {                                                                           \
    _Pragma("unroll") for (int mm = 0; mm < 4; ++mm) {                        \
      _Pragma("unroll") for (int nn = 0; nn < 4; ++nn) {                      \
        acc[(MQ)*4 + mm][nn] = __builtin_amdgcn_mfma_f32_16x16x32_bf16(       \
            a[(MQ)*4 + mm], b[nn], acc[(MQ)*4 + mm][nn], 0, 0, 0);            \
      }                                                                       \
    }                                                                         \
  }

__global__ __launch_bounds__(512, 2)
void k_gemm(const unsigned short* __restrict__ A,   // xb   [NROWS][INDIM] bf16 bits
            const unsigned short* __restrict__ BT,  // encTb[LATDIM][INDIM] bf16 bits
            float* __restrict__ C)                  // latent [NROWS][LATDIM] f32
{
  __shared__ __align__(16) char lds[131072];
  const int tid  = threadIdx.x;
  const int lane = tid & 63, wid = tid >> 6;
  const int wr = wid >> 2, wc = wid & 3;            // 2x4 waves

  // XCD-bijective swizzle: 2048 wgs = 8 XCDs x 256
  const int wg = ((blockIdx.x & 7) << 8) | ((int)blockIdx.x >> 3);
  const int bx = wg & 63, by = wg >> 6;             // 64 col-tiles, 32 row-tiles

  const unsigned short* aT = A  + (size_t)(by * 256) * INDIM;
  const unsigned short* bT = BT + (size_t)(bx * 256) * INDIM;

  auto stage = [&](const unsigned short* gRowBase, int col0, int region) {
    #pragma unroll
    for (int j = 0; j < 2; ++j) {
      const unsigned phys = (unsigned)((j * 8 + wid) * 1024 + lane * 16);
      const unsigned L = phys ^ (((phys >> 7) & 3u) << 4);  // involutive swizzle
      const unsigned row = L >> 6;
      const unsigned s = (L >> 4) & 3u;
      gload16(gRowBase + (size_t)row * INDIM + col0 + s * 8,
              lds + region + (j * 8 + wid) * 1024);
    }
  };

  bf16x8 a[8], b[4];
  auto rdA = [&](int p, int kk) {
    #pragma unroll
    for (int m = 0; m < 8; ++m) {
      const unsigned row = (unsigned)(wr * 128 + m * 16 + (lane & 15));
      const unsigned phys =
          (row * 64 + ((lane >> 4) << 4)) ^ (((row >> 1) & 3u) << 4);
      a[m] = *(const bf16x8*)(lds + AREG(p, kk) + phys);
    }
  };
  auto rdB = [&](int p, int kk) {
    #pragma unroll
    for (int n = 0; n < 4; ++n) {
      const unsigned row = (unsigned)(wc * 64 + n * 16 + (lane & 15));
      const unsigned phys =
          (row * 64 + ((lane >> 4) << 4)) ^ (((row >> 1) & 3u) << 4);
      b[n] = *(const bf16x8*)(lds + BREG(p, kk) + phys);
    }
  };

  const f32x4 fz = {0.f, 0.f, 0.f, 0.f};
  f32x4 acc[8][4];
  #pragma unroll
  for (int m = 0; m < 8; ++m)
    #pragma unroll
    for (int n = 0; n < 4; ++n) acc[m][n] = fz;

  stage(aT, 0,  AREG(0, 0)); stage(bT, 0,  BREG(0, 0));
  stage(aT, 32, AREG(0, 1)); stage(bT, 32, BREG(0, 1));
  stage(aT, 64, AREG(1, 0)); stage(bT, 64, BREG(1, 0));
  asm volatile("s_waitcnt vmcnt(4)" ::: "memory");
  __builtin_amdgcn_s_barrier();

  #pragma unroll 1
  for (int t = 0; t < KTILES; ++t) {
    const int p = t & 1;
    const int k1 = ((t + 1) & (KTILES - 1)) * 64;
    const int k2 = ((t + 2) & (KTILES - 1)) * 64;
    // ---- P1: read kk0 frags, prefetch A-k1(t+1), MFMA quad m0-3 kk0
    rdA(p, 0); rdB(p, 0);
    stage(aT, k1 + 32, AREG(p ^ 1, 1));
    __builtin_amdgcn_s_barrier();
    asm volatile("s_waitcnt lgkmcnt(0)" ::: "memory");
    __builtin_amdgcn_sched_barrier(0);
    __builtin_amdgcn_s_setprio(1);
    MFMAQ(0);
    __builtin_amdgcn_s_setprio(0);
    __builtin_amdgcn_s_barrier();
    // ---- P2: prefetch B-k1(t+1), MFMA quad m4-7 kk0
    stage(bT, k1 + 32, BREG(p ^ 1, 1));
    __builtin_amdgcn_s_barrier();
    __builtin_amdgcn_s_setprio(1);
    MFMAQ(1);
    __builtin_amdgcn_s_setprio(0);
    __builtin_amdgcn_s_barrier();
    // ---- P3: read kk1 frags, prefetch A-k0(t+2), MFMA quad m0-3 kk1
    rdA(p, 1); rdB(p, 1);
    stage(aT, k2, AREG(p, 0));
    __builtin_amdgcn_s_barrier();
    asm volatile("s_waitcnt lgkmcnt(0)" ::: "memory");
    __builtin_amdgcn_sched_barrier(0);
    __builtin_amdgcn_s_setprio(1);
    MFMAQ(0);
    __builtin_amdgcn_s_setprio(0);
    __builtin_amdgcn_s_barrier();
    // ---- P4: prefetch B-k0(t+2), counted wait, MFMA quad m4-7 kk1
    stage(bT, k2, BREG(p, 0));
    asm volatile("s_waitcnt vmcnt(4)" ::: "memory");
    __builtin_amdgcn_s_barrier();
    __builtin_amdgcn_s_setprio(1);
    MFMAQ(1);
    __builtin_amdgcn_s_setprio(0);
    __builtin_amdgcn_s_barrier();
  }
  asm volatile("s_waitcnt vmcnt(0)" ::: "memory");  // drain tail prefetches

  // C/D layout (m89-verified): col = lane&15, row = (lane>>4)*4 + reg
  const int r0  = by * 256 + wr * 128;
  const int c0g = bx * 256 + wc * 64;
  const int cr  = (lane >> 4) * 4;
  const int cc  = lane & 15;
  #pragma unroll
  for (int m = 0; m < 8; ++m)
    #pragma unroll
    for (int n = 0; n < 4; ++n)
      #pragma unroll
      for (int i = 0; i < 4; ++i)
        C[(size_t)(r0 + m * 16 + cr + i) * LATDIM + c0g + n * 16 + cc] =
            acc[m][n][i];
}

// ---------------- K4: exact top-32 selection (2-round 15-way search, 2 count barriers) ----------
__global__ __launch_bounds__(256)
void k_select(const float* __restrict__ latent,
              const float* __restrict__ x,         // exact fp32 x
              const float* __restrict__ encT,      // exact fp32 encoder^T [LATDIM][INDIM]
              int* __restrict__ gIdx, float* __restrict__ gVal) {
  __shared__ float redf[8];
  __shared__ unsigned redc[2][4][8];               // per-round, per-wave packed counts
  __shared__ int   selIdx[TOPK];
  __shared__ float selVal[TOPK];
  __shared__ int   candIdx[CAND_MAX];
  __shared__ float candApp[CAND_MAX];
  __shared__ float candEx[CAND_MAX];
  __shared__ unsigned char candUsed[CAND_MAX];
  __shared__ int nSel, nCand;

  const int tid = threadIdx.x;
  const int lane = tid & 63, wid = tid >> 6;
  const int row = blockIdx.x;
  const float* lrow = latent + (size_t)row * LATDIM;

  // 1. stream row into registers
  float4 v[16];
  {
    const float4* l4 = (const float4*)lrow;
    #pragma unroll
    for (int i = 0; i < 16; ++i) v[i] = l4[i * 256 + tid];
  }
  if (tid == 0) { nSel = 0; nCand = 0; }
  if (tid < TOPK) { selIdx[tid] = 0; selVal[tid] = 0.f; }

  // 2. block min/max
  float mx = -1e30f, mn = 1e30f;
  #pragma unroll
  for (int i = 0; i < 16; ++i) {
    mx = fmaxf(mx, fmaxf(fmaxf(v[i].x, v[i].y), fmaxf(v[i].z, v[i].w)));
    mn = fminf(mn, fminf(fminf(v[i].x, v[i].y), fminf(v[i].z, v[i].w)));
  }
  #pragma unroll
  for (int m2 = 32; m2 >= 1; m2 >>= 1) {
    mx = fmaxf(mx, __shfl_xor(mx, m2, 64));
    mn = fminf(mn, __shfl_xor(mn, m2, 64));
  }
  if (lane == 0) { redf[wid] = mx; redf[4 + wid] = mn; }
  __syncthreads();
  mx = fmaxf(fmaxf(redf[0], redf[1]), fmaxf(redf[2], redf[3]));
  mn = fminf(fminf(redf[4], redf[5]), fminf(redf[6], redf[7]));

  // 3. two 15-way narrowing rounds
  float lo = mn - 0.01f, hi = mx;
  #pragma unroll 1
  for (int r = 0; r < 2; ++r) {
    const float step = (hi - lo) * 0.0625f;
    float t[15];
    #pragma unroll
    for (int j = 0; j < 15; ++j) t[j] = lo + step * (float)(j + 1);
    int c[15];
    #pragma unroll
    for (int j = 0; j < 15; ++j) c[j] = 0;
    #pragma unroll
    for (int i = 0; i < 16; ++i) {
      #pragma unroll
      for (int q = 0; q < 4; ++q) {
        const float f = (q == 0) ? v[i].x : (q == 1) ? v[i].y : (q == 2) ? v[i].z : v[i].w;
        #pragma unroll
        for (int j = 0; j < 15; ++j) c[j] += (f > t[j]) ? 1 : 0;
      }
    }
    // pack 15 counts -> 8 u32 (16-bit fields; wave sums <= 4096, no overflow)
    unsigned p[8];
    #pragma unroll
    for (int k = 0; k < 7; ++k) p[k] = (unsigned)c[2*k] | ((unsigned)c[2*k+1] << 16);
    p[7] = (unsigned)c[14];
    #pragma unroll
    for (int m2 = 32; m2 >= 1; m2 >>= 1) {
      #pragma unroll
      for (int k = 0; k < 8; ++k) p[k] += __shfl_xor(p[k], m2, 64);
    }
    if (lane == 0) {
      #pragma unroll
      for (int k = 0; k < 8; ++k) redc[r][wid][k] = p[k];
    }
    __syncthreads();
    unsigned q2[8];
    #pragma unroll
    for (int k = 0; k < 8; ++k)
      q2[k] = redc[r][0][k] + redc[r][1][k] + redc[r][2][k] + redc[r][3][k];
    int tc[15];
    #pragma unroll
    for (int k = 0; k < 7; ++k) {
      tc[2*k]   = (int)(q2[k] & 0xFFFFu);
      tc[2*k+1] = (int)(q2[k] >> 16);
    }
    tc[14] = (int)q2[7];
    // smallest j with count <= 32 -> hi' = t[j], lo' = t[j-1] (or keep lo)
    float nlo = t[14], nhi = hi;
    #pragma unroll
    for (int j = 14; j >= 0; --j) {
      if (tc[j] <= TOPK) { nhi = t[j]; nlo = (j == 0) ? lo : t[j - 1]; }
    }
    lo = nlo; hi = nhi;
  }

  // 4. classify: certain members and ambiguous candidates
  const float chi = hi + DELTA;
  const float clo = lo - DELTA;
  #pragma unroll
  for (int i = 0; i < 16; ++i) {
    #pragma unroll
    for (int j = 0; j < 4; ++j) {
      const float f = (j == 0) ? v[i].x : (j == 1) ? v[i].y : (j == 2) ? v[i].z : v[i].w;
      const int idx = i * 1024 + tid * 4 + j;
      if (f > chi) {
        int p2 = atomicAdd(&nSel, 1);
        if (p2 < TOPK) { selIdx[p2] = idx; selVal[p2] = f; }
      } else if (f > clo) {
        int p2 = atomicAdd(&nCand, 1);
        if (p2 < CAND_MAX) { candIdx[p2] = idx; candApp[p2] = f; }
      }
    }
  }
  __syncthreads();

  // 5. exact fp32 recompute of candidates (one wave per candidate)
  const int nc = min(nCand, CAND_MAX);
  const float* xr = x + (size_t)row * INDIM;
  for (int c2 = wid; c2 < nc; c2 += 4) {
    const float* er = encT + (size_t)candIdx[c2] * INDIM;
    float acc = 0.f;
    for (int k = lane; k < INDIM; k += 64)
      acc = fmaf(xr[k], er[k], acc);
    #pragma unroll
    for (int m2 = 32; m2 >= 1; m2 >>= 1)
      acc += __shfl_xor(acc, m2, 64);
    if (lane == 0) candEx[c2] = acc;
  }
  __syncthreads();

  // 6. resolve membership among candidates by exact value (ties -> lower index)
  if (tid == 0) {
    int ns = min(nSel, TOPK);
    int needF = TOPK - ns;
    for (int c2 = 0; c2 < nc; ++c2) candUsed[c2] = 0;
    int filled = 0;
    for (int t2 = 0; t2 < needF; ++t2) {
      int best = -1;
      for (int c2 = 0; c2 < nc; ++c2) {
        if (candUsed[c2]) continue;
        if (best < 0 || candEx[c2] > candEx[best] ||
            (candEx[c2] == candEx[best] && candIdx[c2] < candIdx[best]))
          best = c2;
      }
      if (best < 0) break;
      candUsed[best] = 1;
      selIdx[ns + filled] = candIdx[best];
      selVal[ns + filled] = candApp[best];
      ++filled;
    }
  }
  __syncthreads();

  // 7. emit lists
  if (tid < TOPK) {
    gIdx[(size_t)row * TOPK + tid] = selIdx[tid];
    gVal[(size_t)row * TOPK + tid] = selVal[tid];
  }
}

// ---------------- K4b: streaming zeros + scatter (4 rows/block, disjoint ownership) ----------
// 4 rows = 4*16384 floats = 16384 float4 = 64 iters * 256 threads (R4 bug: was 16 iters -> 1 row)
__global__ __launch_bounds__(256)
void k_scatter(float* __restrict__ sparse,
               const int* __restrict__ gIdx, const float* __restrict__ gVal) {
  const int tid = threadIdx.x;
  const int r0 = blockIdx.x * 4;
  float4* base = (float4*)(sparse + (size_t)r0 * LATDIM);
  const float4 z = {0.f, 0.f, 0.f, 0.f};
  #pragma unroll
  for (int i = 0; i < 64; ++i) base[i * 256 + tid] = z;   // 4 rows x 4096 f4
  __syncthreads();
  if (tid < 4 * TOPK) {
    const int r = r0 + (tid >> 5);
    const int k = tid & 31;
    const int idx = gIdx[(size_t)r * TOPK + k];
    const float val = gVal[(size_t)r * TOPK + k];
    sparse[(size_t)r * LATDIM + idx] = val;
  }
}

// ---------------- K5: decode (32 AXPYs of decoder rows per x-row) ----------------
__global__ __launch_bounds__(256)
void k_decode(const int* __restrict__ gIdx, const float* __restrict__ gVal,
              const float* __restrict__ dec, float* __restrict__ recon) {
  __shared__ int   sidx[TOPK];
  __shared__ float sval[TOPK];
  const int tid = threadIdx.x, row = blockIdx.x;
  if (tid < TOPK) {
    sidx[tid] = gIdx[(size_t)row * TOPK + tid];
    sval[tid] = gVal[(size_t)row * TOPK + tid];
  }
  __syncthreads();
  float4 a0 = {0.f,0.f,0.f,0.f}, a1 = {0.f,0.f,0.f,0.f};
  #pragma unroll 4
  for (int k = 0; k < TOPK; ++k) {
    const float v = sval[k];
    const float4* dr = (const float4*)(dec + (size_t)sidx[k] * HIDDIM);
    float4 d0 = dr[tid], d1 = dr[tid + 256];
    a0.x = fmaf(v, d0.x, a0.x); a0.y = fmaf(v, d0.y, a0.y);
    a0.z = fmaf(v, d0.z, a0.z); a0.w = fmaf(v, d0.w, a0.w);
    a1.x = fmaf(v, d1.x, a1.x); a1.y = fmaf(v, d1.y, a1.y);
    a1.z = fmaf(v, d1.z, a1.z); a1.w = fmaf(v, d1.w, a1.w);
  }
  float4* orow = (float4*)(recon + (size_t)row * HIDDIM);
  orow[tid] = a0; orow[tid + 256] = a1;
}

extern "C" void kernel_launch(void* const* d_in, const int* in_sizes, int n_in,
                              void* d_out, int out_size, void* d_ws, size_t ws_size,
                              hipStream_t stream) {
  (void)in_sizes; (void)n_in; (void)out_size; (void)ws_size;
  const float* x   = (const float*)d_in[0];   // [8192][2048]
  const float* enc = (const float*)d_in[1];   // [2048][16384]
  const float* dec = (const float*)d_in[2];   // [16384][2048]

  float* recon  = (float*)d_out;                        // [8192][2048]
  float* sparse = recon + (size_t)NROWS * HIDDIM;       // [8192][16384] (also latent scratch)

  // ws layout (~226 MB needed)
  char* w = (char*)d_ws;
  unsigned short* xb    = (unsigned short*)w;                             // 32 MB
  unsigned short* encTb = (unsigned short*)(w + (size_t)33554432);        // 64 MB
  float*          encT  = (float*)(w + (size_t)100663296);                // 128 MB
  int*            gIdx  = (int*)(w + (size_t)234881024);                  // 1 MB
  float*          gVal  = (float*)(w + (size_t)235929600);                // 1 MB

  k_cvt_x<<<(NROWS * INDIM / 4 + 255) / 256, 256, 0, stream>>>(
      (const float4*)x, (ushort4*)xb, NROWS * INDIM / 4);
  k_trans_enc<<<dim3(LATDIM / 32, INDIM / 32), dim3(32, 8), 0, stream>>>(enc, encT, encTb);
  k_gemm<<<dim3((NROWS / 256) * (LATDIM / 256)), 512, 0, stream>>>(xb, encTb, sparse);
  k_select<<<NROWS, 256, 0, stream>>>(sparse, x, encT, gIdx, gVal);
  k_scatter<<<NROWS / 4, 256, 0, stream>>>(sparse, gIdx, gVal);
  k_decode<<<NROWS, 256, 0, stream>>>(gIdx, gVal, dec, recon);
}